// Round 7
// baseline (1563.089 us; speedup 1.0000x reference)
//
#include <hip/hip_runtime.h>
#include <hip/hip_bf16.h>
#include <math.h>

#define Bz 8
#define Sz 1024
#define INz 128
#define Ez 512
#define Hz 8
#define HDz 64
#define FFz 2048
#define Lz 4
#define Nz (Bz*Sz)   // 8192
#define EPSf 1e-5f

typedef __attribute__((ext_vector_type(8))) short short8;
typedef __attribute__((ext_vector_type(4))) float floatx4;
#define MFMA16(a,b,c) __builtin_amdgcn_mfma_f32_16x16x32_bf16(a,b,c,0,0,0)

typedef __hip_bfloat16 bf16;

__device__ inline float b2f(bf16 v) { return __bfloat162float(v); }
__device__ inline bf16 f2b(float v) { return __float2bfloat16(v); }

// async global->LDS, 16B per lane, wave-uniform LDS base (HW adds lane*16)
__device__ inline void gload16(const bf16* g, bf16* lds_base)
{
  __builtin_amdgcn_global_load_lds(
      (const __attribute__((address_space(1))) void*)g,
      (__attribute__((address_space(3))) void*)lds_base,
      16, 0, 0);
}

#define FENCE() asm volatile("" ::: "memory")
#define PB() do { FENCE(); __builtin_amdgcn_s_barrier(); FENCE(); } while (0)
#define VMCNT0() asm volatile("s_waitcnt vmcnt(0)" ::: "memory")
#define VMCNT8() asm volatile("s_waitcnt vmcnt(8)" ::: "memory")

// ---------------- fp32 -> bf16 cast
__global__ __launch_bounds__(256) void cast_f2b(const float* __restrict__ in,
    bf16* __restrict__ out, int n)
{
  int i = blockIdx.x * 256 + threadIdx.x;
  if (i < n) out[i] = f2b(in[i]);
}

// ---------------- 256x256 8-phase bf16 NT GEMM (T3+T4+T5 structure)
__global__ __launch_bounds__(512, 1) void gemm256(
    const bf16* __restrict__ A, const bf16* __restrict__ Wm,
    const float* __restrict__ bias, bf16* __restrict__ Cb,
    int N, int K, int relu)
{
  int gx = gridDim.x, nwg = gx * gridDim.y;
  int flat = blockIdx.y * gx + blockIdx.x;
  if (!(nwg & 7)) {                      // bijective chunked XCD swizzle
    int cpx = nwg >> 3;
    flat = (flat & 7) * cpx + (flat >> 3);
  }
  int bm = (flat / gx) * 256, bn = (flat % gx) * 256;
  __shared__ __align__(16) bf16 As0[256][64], Bs0[256][64];
  __shared__ __align__(16) bf16 As1[256][64], Bs1[256][64];
  int t = threadIdx.x, wave = t >> 6, lane = t & 63;
  int wm = (wave >> 2) * 128, wn = (wave & 3) * 64;
  int fr = lane & 15, fo = lane >> 4;       // fragment row / chunk group
  int w8 = wave * 8, lrow = lane >> 3;
  int sc8 = ((lane & 7) ^ (lrow & 7)) * 8;  // swizzled source col (bf16)
  floatx4 acc[8][4];
  #pragma unroll
  for (int i = 0; i < 8; ++i)
    #pragma unroll
    for (int j = 0; j < 4; ++j) acc[i][j] = (floatx4){0.f, 0.f, 0.f, 0.f};

  #define STAGE8(DA, DB, kk) do {                                           \
    _Pragma("unroll")                                                        \
    for (int c_ = 0; c_ < 4; ++c_) {                                         \
      int row_ = c_ * 64 + w8 + lrow;                                        \
      gload16(A  + (size_t)(bm + row_) * K + (kk) + sc8, &DA[c_ * 64 + w8][0]);\
      gload16(Wm + (size_t)(bn + row_) * K + (kk) + sc8, &DB[c_ * 64 + w8][0]);\
    } } while (0)

  #define TILE(AA, BB, SA, SB, kk, DOSTAGE) do {                            \
    _Pragma("unroll")                                                        \
    for (int q_ = 0; q_ < 4; ++q_) {                                         \
      short8 a_[4][2], bf_[2][2];                                            \
      _Pragma("unroll")                                                      \
      for (int j_ = 0; j_ < 4; ++j_) {                                       \
        int row_ = wm + ((q_ >> 1) * 4 + j_) * 16 + fr;                      \
        a_[j_][0] = *(const short8*)&AA[row_][((fo) ^ (fr & 7)) * 8];        \
        a_[j_][1] = *(const short8*)&AA[row_][((4 + fo) ^ (fr & 7)) * 8];    \
      }                                                                      \
      _Pragma("unroll")                                                      \
      for (int g_ = 0; g_ < 2; ++g_) {                                       \
        int row_ = wn + ((q_ & 1) * 2 + g_) * 16 + fr;                       \
        bf_[g_][0] = *(const short8*)&BB[row_][((fo) ^ (fr & 7)) * 8];       \
        bf_[g_][1] = *(const short8*)&BB[row_][((4 + fo) ^ (fr & 7)) * 8];   \
      }                                                                      \
      if ((DOSTAGE) && q_ == 0) STAGE8(SA, SB, kk);                          \
      PB();                                                                  \
      __builtin_amdgcn_s_setprio(1);                                         \
      _Pragma("unroll")                                                      \
      for (int j_ = 0; j_ < 4; ++j_)                                         \
        _Pragma("unroll")                                                    \
        for (int g_ = 0; g_ < 2; ++g_) {                                     \
          int fi_ = (q_ >> 1) * 4 + j_, gi_ = (q_ & 1) * 2 + g_;             \
          acc[fi_][gi_] = MFMA16(a_[j_][0], bf_[g_][0], acc[fi_][gi_]);      \
          acc[fi_][gi_] = MFMA16(a_[j_][1], bf_[g_][1], acc[fi_][gi_]);      \
        }                                                                    \
      __builtin_amdgcn_s_setprio(0);                                         \
      if (q_ == 3) VMCNT0();                                                 \
      PB();                                                                  \
    } } while (0)

  int nt = K >> 6;                // even, >= 2
  STAGE8(As0, Bs0, 0);
  STAGE8(As1, Bs1, 64);
  VMCNT8();                       // tile0 ready; tile1 stays in flight
  PB();
  TILE(As0, Bs0, As0, Bs0, 0, 0);                 // tile 0 (no stage)
  for (int i = 1; i + 2 < nt; i += 2) {
    TILE(As1, Bs1, As0, Bs0, (i + 1) * 64, 1);    // odd tile, stage even
    TILE(As0, Bs0, As1, Bs1, (i + 2) * 64, 1);    // even tile, stage odd
  }
  TILE(As1, Bs1, As0, Bs0, 0, 0);                 // tile nt-1 (no stage)
  #undef STAGE8
  #undef TILE

  #pragma unroll
  for (int f = 0; f < 8; ++f) {
    #pragma unroll
    for (int r = 0; r < 4; ++r) {
      int row = bm + wm + f * 16 + (lane >> 4) * 4 + r;
      #pragma unroll
      for (int g = 0; g < 4; ++g) {
        int col = bn + wn + g * 16 + fr;
        float v = acc[f][g][r] + (bias ? bias[col] : 0.f);
        if (relu) v = fmaxf(v, 0.f);
        Cb[(size_t)row * N + col] = f2b(v);
      }
    }
  }
}

// ---------------- unified bf16 MFMA NT GEMM (128x128, 2-phase dbuf)
__global__ __launch_bounds__(256) void gemm_bt(
    const bf16* __restrict__ A, const bf16* __restrict__ Wm,
    const float* __restrict__ bias, float* __restrict__ Cf,
    bf16* __restrict__ Cb, const float* __restrict__ rowscale,
    int M, int N, int K, long sA, long sW, long sC, int relu)
{
  int z = blockIdx.z;
  A  += (size_t)z * sA;
  Wm += (size_t)z * sW;
  if (rowscale) rowscale += (size_t)z * M;
  size_t cbase = (size_t)z * sC;
  int bm = blockIdx.y * 128, bn = blockIdx.x * 128;
  __shared__ __align__(16) bf16 As0[128][64], Bs0[128][64];
  __shared__ __align__(16) bf16 As1[128][64], Bs1[128][64];
  int t = threadIdx.x, wave = t >> 6, lane = t & 63;
  int wm = (wave >> 1) * 64, wn = (wave & 1) * 64;
  int fr = lane & 15, fo = lane >> 4;
  int srow = lane >> 3;
  int scol = ((lane & 7) ^ srow) * 8;
  floatx4 acc[4][4];
  #pragma unroll
  for (int i = 0; i < 4; ++i)
    #pragma unroll
    for (int j = 0; j < 4; ++j) acc[i][j] = (floatx4){0.f, 0.f, 0.f, 0.f};

  #define STAGE(Ad, Bd, kk) do {                                            \
    _Pragma("unroll")                                                        \
    for (int i_ = 0; i_ < 4; ++i_) {                                         \
      int chunk_ = wave * 4 + i_;                                            \
      int row_ = chunk_ * 8 + srow;                                          \
      gload16(A  + (size_t)(bm + row_) * K + (kk) + scol, &Ad[chunk_ * 8][0]);\
      gload16(Wm + (size_t)(bn + row_) * K + (kk) + scol, &Bd[chunk_ * 8][0]);\
    } } while (0)

  #define COMPUTE(Ad, Bd) do {                                               \
    _Pragma("unroll")                                                        \
    for (int ks_ = 0; ks_ < 2; ++ks_) {                                      \
      int sw_ = ((ks_ * 4 + fo) ^ (fr & 7)) * 8;                             \
      short8 af_[4], bf_[4];                                                 \
      _Pragma("unroll")                                                      \
      for (int rt_ = 0; rt_ < 4; ++rt_)                                      \
        af_[rt_] = *(const short8*)&Ad[wm + rt_ * 16 + fr][sw_];             \
      _Pragma("unroll")                                                      \
      for (int ct_ = 0; ct_ < 4; ++ct_)                                      \
        bf_[ct_] = *(const short8*)&Bd[wn + ct_ * 16 + fr][sw_];             \
      _Pragma("unroll")                                                      \
      for (int rt_ = 0; rt_ < 4; ++rt_)                                      \
        _Pragma("unroll")                                                    \
        for (int ct_ = 0; ct_ < 4; ++ct_)                                    \
          acc[rt_][ct_] = MFMA16(af_[rt_], bf_[ct_], acc[rt_][ct_]);         \
    } } while (0)

  STAGE(As0, Bs0, 0);
  __syncthreads();
  for (int k0 = 0; k0 < K; k0 += 128) {
    if (k0 + 64 < K) STAGE(As1, Bs1, k0 + 64);
    COMPUTE(As0, Bs0);
    __syncthreads();
    if (k0 + 64 < K) {
      if (k0 + 128 < K) STAGE(As0, Bs0, k0 + 128);
      COMPUTE(As1, Bs1);
      __syncthreads();
    }
  }
  #undef STAGE
  #undef COMPUTE

  #pragma unroll
  for (int rt = 0; rt < 4; ++rt) {
    #pragma unroll
    for (int r = 0; r < 4; ++r) {
      int row = bm + wm + rt * 16 + (lane >> 4) * 4 + r;
      float rs = rowscale ? (1.f / rowscale[row]) : 1.f;
      #pragma unroll
      for (int ct = 0; ct < 4; ++ct) {
        int col = bn + wn + ct * 16 + fr;
        float v = acc[rt][ct][r] + (bias ? bias[col] : 0.f);
        if (relu) v = fmaxf(v, 0.f);
        v *= rs;
        if (Cf) Cf[cbase + (size_t)row * N + col] = v;
        if (Cb) Cb[cbase + (size_t)row * N + col] = f2b(v);
      }
    }
  }
}

// ---------------- BatchNorm stats over N rows, per channel
__global__ __launch_bounds__(256) void bn_stats(const float* __restrict__ x, float* __restrict__ st)
{
  int c = blockIdx.x;
  float s = 0.f, q = 0.f;
  for (int r = threadIdx.x; r < Nz; r += 256) {
    float v = x[(size_t)r * Ez + c];
    s += v; q += v * v;
  }
  for (int o = 32; o; o >>= 1) { s += __shfl_down(s, o); q += __shfl_down(q, o); }
  __shared__ float shs[4], shq[4];
  int w = threadIdx.x >> 6;
  if ((threadIdx.x & 63) == 0) { shs[w] = s; shq[w] = q; }
  __syncthreads();
  if (threadIdx.x == 0) {
    s = shs[0] + shs[1] + shs[2] + shs[3];
    q = shq[0] + shq[1] + shq[2] + shq[3];
    float mu = s / (float)Nz;
    float var = q / (float)Nz - mu * mu;
    st[c] = mu;
    st[Ez + c] = rsqrtf(var + EPSf);
  }
}

// ---------------- BN apply + positional encoding -> x fp32 and xb bf16
__global__ __launch_bounds__(256) void bn_apply_pe(const float* __restrict__ x0,
    const float* __restrict__ st, const float* __restrict__ g,
    const float* __restrict__ b, float* __restrict__ x, bf16* __restrict__ xb)
{
  int idx = blockIdx.x * 256 + threadIdx.x;
  int c = idx & (Ez - 1);
  int r = idx >> 9;
  int s = r & (Sz - 1);
  float dt = expf((float)(c & ~1) * (-9.210340371976184f / (float)Ez));
  float ang = (float)s * dt;
  float pe = (c & 1) ? cosf(ang) : sinf(ang);
  float mu = st[c], rs = st[Ez + c];
  float v = (x0[idx] - mu) * rs * g[c] + b[c] + pe;
  x[idx] = v;
  xb[idx] = f2b(v);
}

// ---------------- distance bias -> bf16
__global__ __launch_bounds__(256) void dist_bias_k(const float* __restrict__ dist,
    const float* __restrict__ dsc, bf16* __restrict__ db)
{
  size_t base = (size_t)blockIdx.x * Sz;
  float m = -1e30f;
  for (int j = threadIdx.x; j < Sz; j += 256) m = fmaxf(m, dist[base + j]);
  for (int o = 32; o; o >>= 1) m = fmaxf(m, __shfl_down(m, o));
  __shared__ float sh[4];
  if ((threadIdx.x & 63) == 0) sh[threadIdx.x >> 6] = m;
  __syncthreads();
  m = fmaxf(fmaxf(sh[0], sh[1]), fmaxf(sh[2], sh[3]));
  float sc = dsc[0];
  float inv = 1.f / m;
  for (int j = threadIdx.x; j < Sz; j += 256)
    db[base + j] = f2b(expf(sc * (1.f - dist[base + j] * inv)));
}

// ---------------- transpose xb [B*S,E] -> xT [B][E][S]
__global__ __launch_bounds__(256) void transpose_xb(const bf16* __restrict__ xb,
    bf16* __restrict__ xT)
{
  int b = blockIdx.z, e0 = blockIdx.y * 32, s0 = blockIdx.x * 32;
  __shared__ bf16 T[32][40];
  int t = threadIdx.x, row = t >> 3, c = t & 7;
  *(ushort4*)&T[row][c * 4] = *(const ushort4*)(xb + (size_t)(b * Sz + s0 + row) * Ez + e0 + c * 4);
  __syncthreads();
  ushort4 v;
  unsigned short* vp = (unsigned short*)&v;
  #pragma unroll
  for (int i = 0; i < 4; ++i) vp[i] = *(const unsigned short*)&T[c * 4 + i][row];
  *(ushort4*)(xT + ((size_t)b * Ez + e0 + row) * Sz + s0 + c * 4) = v;
}

// ---------------- MFMA attention stats: per (b,h,q) running max m and sum Z
// gload16-staged (linear+swizzle), K double-buffered: prefetch tile i+1
// while computing tile i (softmax VALU hides L2 latency).
// Also zeroes den (h==0 blocks) for scores_bias's atomic row sums.
__global__ __launch_bounds__(256) void attn_stats2(const bf16* __restrict__ qk,
    float* __restrict__ stats, float* __restrict__ den)
{
  int qt = blockIdx.x, h = blockIdx.y, b = blockIdx.z;
  int q0 = qt * 64;
  int t = threadIdx.x, wave = t >> 6, lane = t & 63;
  if (h == 0 && t < 64) den[(size_t)b * Sz + q0 + t] = 0.f;
  __shared__ __align__(16) bf16 Qs[64][64];
  __shared__ __align__(16) bf16 Ks0[128][64], Ks1[128][64];
  int fr = lane & 15, fo = lane >> 4;
  int srow = lane >> 3;
  int scol = ((lane & 7) ^ srow) * 8;
  int sw0 = ((fo) ^ (fr & 7)) * 8, sw1 = ((4 + fo) ^ (fr & 7)) * 8;

  // stage Q (64x64) once: chunks 0..7
  #pragma unroll
  for (int i = 0; i < 2; ++i) {
    int chunk = wave * 2 + i, row = chunk * 8 + srow;
    gload16(qk + (size_t)(b * Sz + q0 + row) * 1024 + h * 64 + scol, &Qs[chunk * 8][0]);
  }
  #define STAGEK(Kd, kk) do {                                                \
    _Pragma("unroll")                                                        \
    for (int i_ = 0; i_ < 4; ++i_) {                                         \
      int chunk_ = wave * 4 + i_, row_ = chunk_ * 8 + srow;                  \
      gload16(qk + (size_t)(b * Sz + (kk) + row_) * 1024 + 512 + h * 64 + scol,\
              &Kd[chunk_ * 8][0]);                                           \
    } } while (0)

  STAGEK(Ks0, 0);
  __syncthreads();
  short8 aq0 = *(const short8*)&Qs[wave * 16 + fr][sw0];
  short8 aq1 = *(const short8*)&Qs[wave * 16 + fr][sw1];
  float m_run[4] = {-1e30f, -1e30f, -1e30f, -1e30f};
  float z_run[4] = {0.f, 0.f, 0.f, 0.f};

  #define KCOMP(Kd) do {                                                     \
    float sc[8][4];                                                          \
    _Pragma("unroll")                                                        \
    for (int j = 0; j < 8; ++j) {                                            \
      floatx4 a4 = (floatx4){0.f, 0.f, 0.f, 0.f};                            \
      short8 b0 = *(const short8*)&Kd[j * 16 + fr][sw0];                     \
      short8 b1 = *(const short8*)&Kd[j * 16 + fr][sw1];                     \
      a4 = MFMA16(aq0, b0, a4);                                              \
      a4 = MFMA16(aq1, b1, a4);                                              \
      _Pragma("unroll")                                                      \
      for (int r = 0; r < 4; ++r) sc[j][r] = a4[r] * 0.125f;                 \
    }                                                                        \
    _Pragma("unroll")                                                        \
    for (int r = 0; r < 4; ++r) {                                            \
      float vm = sc[0][r];                                                   \
      _Pragma("unroll")                                                      \
      for (int j = 1; j < 8; ++j) vm = fmaxf(vm, sc[j][r]);                  \
      _Pragma("unroll")                                                      \
      for (int o = 1; o < 16; o <<= 1) vm = fmaxf(vm, __shfl_xor(vm, o, 16));\
      float mn = fmaxf(m_run[r], vm);                                        \
      float zb = 0.f;                                                        \
      _Pragma("unroll")                                                      \
      for (int j = 0; j < 8; ++j) zb += __expf(sc[j][r] - mn);               \
      _Pragma("unroll")                                                      \
      for (int o = 1; o < 16; o <<= 1) zb += __shfl_xor(zb, o, 16);          \
      z_run[r] = z_run[r] * __expf(m_run[r] - mn) + zb;                      \
      m_run[r] = mn;                                                         \
    } } while (0)

  for (int k0 = 0; k0 < Sz; k0 += 256) {
    STAGEK(Ks1, k0 + 128);            // prefetch overlaps compute
    KCOMP(Ks0);
    __syncthreads();
    if (k0 + 256 < Sz) STAGEK(Ks0, k0 + 256);
    KCOMP(Ks1);
    __syncthreads();
  }
  #undef STAGEK
  #undef KCOMP

  if (fr == 0) {
    int qb = q0 + wave * 16 + (lane >> 4) * 4;
    #pragma unroll
    for (int r = 0; r < 4; ++r) {
      size_t o = ((size_t)(b * Hz + h) * Sz + qb + r) * 2;
      stats[o] = m_run[r];
      stats[o + 1] = z_run[r];
    }
  }
}

// ---------------- MFMA scores: aw[b,q,k] = (1/H * sum_h softmax_h) * db (bf16)
// 128x128 tile, gload16-staged (linear+swizzle), head double-buffered:
// head h+1 prefetched while computing head h (exp VALU hides L2 latency).
// + fused row-sum via wave reduce + atomicAdd -> den.
__global__ __launch_bounds__(256) void scores_bias(const bf16* __restrict__ qk,
    const bf16* __restrict__ db, const float* __restrict__ stats,
    bf16* __restrict__ aw, float* __restrict__ den)
{
  int kt = blockIdx.x, qt = blockIdx.y, b = blockIdx.z;
  int q0 = qt * 128, k0 = kt * 128;
  __shared__ __align__(16) bf16 Qs0[128][64], Ks0[128][64];
  __shared__ __align__(16) bf16 Qs1[128][64], Ks1[128][64];
  __shared__ float mS[128][9];
  __shared__ float ziS[128][9];
  int t = threadIdx.x, wave = t >> 6, lane = t & 63;
  int fr = lane & 15, fo = lane >> 4;
  int wm = (wave >> 1) * 64, wn = (wave & 1) * 64;
  int srow = lane >> 3;
  int scol = ((lane & 7) ^ srow) * 8;
  int sw0 = ((fo) ^ (fr & 7)) * 8, sw1 = ((4 + fo) ^ (fr & 7)) * 8;

  #pragma unroll
  for (int i = 0; i < 4; ++i) {
    int lin = i * 256 + t, h = lin >> 7, q = lin & 127;
    const float* sp = stats + ((size_t)(b * Hz + h) * Sz + q0 + q) * 2;
    mS[q][h] = sp[0];
    ziS[q][h] = 1.f / sp[1];
  }

  floatx4 pac[4][4];
  #pragma unroll
  for (int i = 0; i < 4; ++i)
    #pragma unroll
    for (int j = 0; j < 4; ++j) pac[i][j] = (floatx4){0.f, 0.f, 0.f, 0.f};

  #define STAGEH(Qd, Kd, hh) do {                                            \
    _Pragma("unroll")                                                        \
    for (int i_ = 0; i_ < 4; ++i_) {                                         \
      int chunk_ = wave * 4 + i_, row_ = chunk_ * 8 + srow;                  \
      gload16(qk + (size_t)(b * Sz + q0 + row_) * 1024 + (hh) * 64 + scol,   \
              &Qd[chunk_ * 8][0]);                                           \
      gload16(qk + (size_t)(b * Sz + k0 + row_) * 1024 + 512 + (hh) * 64 + scol,\
              &Kd[chunk_ * 8][0]);                                           \
    } } while (0)

  #define HCOMP(Qd, Kd, hh) do {                                             \
    short8 bfv0[4], bfv1[4];                                                 \
    _Pragma("unroll")                                                        \
    for (int ct = 0; ct < 4; ++ct) {                                         \
      bfv0[ct] = *(const short8*)&Kd[wn + ct * 16 + fr][sw0];                \
      bfv1[ct] = *(const short8*)&Kd[wn + ct * 16 + fr][sw1];                \
    }                                                                        \
    _Pragma("unroll")                                                        \
    for (int rt = 0; rt < 4; ++rt) {                                         \
      short8 af0 = *(const short8*)&Qd[wm + rt * 16 + fr][sw0];              \
      short8 af1 = *(const short8*)&Qd[wm + rt * 16 + fr][sw1];              \
      floatx4 sc[4];                                                         \
      _Pragma("unroll")                                                      \
      for (int ct = 0; ct < 4; ++ct) {                                       \
        floatx4 z4 = (floatx4){0.f, 0.f, 0.f, 0.f};                          \
        z4 = MFMA16(af0, bfv0[ct], z4);                                      \
        sc[ct] = MFMA16(af1, bfv1[ct], z4);                                  \
      }                                                                      \
      _Pragma("unroll")                                                      \
      for (int r = 0; r < 4; ++r) {                                          \
        int qloc = wm + rt * 16 + (lane >> 4) * 4 + r;                       \
        float m = mS[qloc][hh], zi = ziS[qloc][hh];                          \
        _Pragma("unroll")                                                    \
        for (int ct = 0; ct < 4; ++ct)                                       \
          pac[rt][ct][r] += __expf(sc[ct][r] * 0.125f - m) * zi;             \
      }                                                                      \
    } } while (0)

  STAGEH(Qs0, Ks0, 0);
  __syncthreads();   // also covers mS/ziS writes
  #pragma unroll
  for (int h = 0; h < 8; h += 2) {
    STAGEH(Qs1, Ks1, h + 1);          // prefetch overlaps compute
    HCOMP(Qs0, Ks0, h);
    __syncthreads();
    if (h + 2 < 8) STAGEH(Qs0, Ks0, h + 2);
    HCOMP(Qs1, Ks1, h + 1);
    __syncthreads();
  }
  #undef STAGEH
  #undef HCOMP

  #pragma unroll
  for (int rt = 0; rt < 4; ++rt) {
    #pragma unroll
    for (int r = 0; r < 4; ++r) {
      int qloc = wm + rt * 16 + (lane >> 4) * 4 + r;
      size_t rowoff = (size_t)(b * Sz + q0 + qloc) * Sz + k0;
      float rsum = 0.f;
      #pragma unroll
      for (int ct = 0; ct < 4; ++ct) {
        int kloc = wn + ct * 16 + fr;
        float p = pac[rt][ct][r] * 0.125f * b2f(db[rowoff + kloc]);
        aw[rowoff + kloc] = f2b(p);
        rsum += p;
      }
      #pragma unroll
      for (int o = 1; o < 16; o <<= 1) rsum += __shfl_xor(rsum, o, 16);
      if (fr == 0) atomicAdd(den + (size_t)b * Sz + q0 + qloc, rsum);
    }
  }
}

// ---------------- residual add + LayerNorm -> x fp32, xb bf16 (float2 vec)
__global__ __launch_bounds__(256) void add_ln(const float* __restrict__ xin,
    const float* __restrict__ dly, const float* __restrict__ g,
    const float* __restrict__ bb, float* __restrict__ xout, bf16* __restrict__ xbout)
{
  size_t base = (size_t)blockIdx.x * Ez;
  int t = threadIdx.x;
  float2 xi = *(const float2*)(xin + base + t * 2);
  float2 dl = *(const float2*)(dly + base + t * 2);
  float a0 = xi.x + dl.x;
  float a1 = xi.y + dl.y;
  float s = a0 + a1, q = a0 * a0 + a1 * a1;
  for (int o = 32; o; o >>= 1) { s += __shfl_down(s, o); q += __shfl_down(q, o); }
  __shared__ float shs[4], shq[4];
  if ((t & 63) == 0) { shs[t >> 6] = s; shq[t >> 6] = q; }
  __syncthreads();
  s = shs[0] + shs[1] + shs[2] + shs[3];
  q = shq[0] + shq[1] + shq[2] + shq[3];
  float mu = s * (1.f / Ez);
  float var = q * (1.f / Ez) - mu * mu;
  float rs = rsqrtf(var + EPSf);
  float v0 = (a0 - mu) * rs * g[t * 2] + bb[t * 2];
  float v1 = (a1 - mu) * rs * g[t * 2 + 1] + bb[t * 2 + 1];
  float2 vo; vo.x = v0; vo.y = v1;
  *(float2*)(xout + base + t * 2) = vo;
  bf16 b0 = f2b(v0), b1 = f2b(v1);
  ushort2 pk;
  pk.x = *(unsigned short*)&b0;
  pk.y = *(unsigned short*)&b1;
  *(ushort2*)(xbout + base + t * 2) = pk;
}

extern "C" void kernel_launch(void* const* d_in, const int* in_sizes, int n_in,
                              void* d_out, int out_size, void* d_ws, size_t ws_size,
                              hipStream_t stream)
{
  const float* src        = (const float*)d_in[0];
  const float* distances  = (const float*)d_in[1];
  const float* proj_w     = (const float*)d_in[2];
  const float* proj_b     = (const float*)d_in[3];
  const float* bn_g       = (const float*)d_in[4];
  const float* bn_b       = (const float*)d_in[5];
  const float* in_proj_w  = (const float*)d_in[6];
  const float* in_proj_b  = (const float*)d_in[7];
  const float* dist_scale = (const float*)d_in[8];
  const float* lin1_w     = (const float*)d_in[9];
  const float* lin1_b     = (const float*)d_in[10];
  const float* lin2_w     = (const float*)d_in[11];
  const float* lin2_b     = (const float*)d_in[12];
  const float* n1_g       = (const float*)d_in[13];
  const float* n1_b       = (const float*)d_in[14];
  const float* n2_g       = (const float*)d_in[15];
  const float* n2_b       = (const float*)d_in[16];

  float* x = (float*)d_out;                      // fp32 activations [N,E]

  // workspace layout (≈88 MB)
  float* stats = (float*)d_ws;                   // B*H*S*2
  float* den   = stats + 131072;                 // B*S
  float* bnst  = den + 8192;                     // 2*E
  float* aout  = bnst + 1024;                    // N*E fp32
  float* x0    = aout;                           // alias (pre-loop only)
  bf16* db_b = (bf16*)(aout + (size_t)Nz * Ez);  // B*S*S
  bf16* Rqk  = db_b + (size_t)Bz * Sz * Sz;      // union region: qk+aw | ff1
  bf16* qk   = Rqk;                              // N*1024
  bf16* aw   = Rqk + (size_t)Nz * 1024;          // B*S*S
  bf16* ff1  = Rqk;                              // N*FF (aliases qk+aw, disjoint lifetime)
  bf16* xb   = Rqk + (size_t)Nz * FFz;           // N*E
  bf16* xT   = xb + (size_t)Nz * Ez;             // B*E*S
  bf16* srcb = xT + (size_t)Bz * Ez * Sz;        // N*IN
  bf16* wpr  = srcb + (size_t)Nz * INz;          // E*IN
  bf16* wqk  = wpr + Ez * INz;                   // 1024*E (q,k rows only)
  bf16* wl1  = wqk + 1024 * Ez;                  // FF*E
  bf16* wl2  = wl1 + FFz * Ez;                   // E*FF

  // weight / input casts
  cast_f2b<<<(Nz * INz) / 256, 256, 0, stream>>>(src, srcb, Nz * INz);
  cast_f2b<<<(Ez * INz + 255) / 256, 256, 0, stream>>>(proj_w, wpr, Ez * INz);
  cast_f2b<<<(1024 * Ez) / 256, 256, 0, stream>>>(in_proj_w, wqk, 1024 * Ez);
  cast_f2b<<<(FFz * Ez) / 256, 256, 0, stream>>>(lin1_w, wl1, FFz * Ez);
  cast_f2b<<<(Ez * FFz) / 256, 256, 0, stream>>>(lin2_w, wl2, Ez * FFz);

  // input projection -> x0 fp32
  gemm_bt<<<dim3(Ez / 128, Nz / 128, 1), 256, 0, stream>>>(
      srcb, wpr, proj_b, x0, nullptr, nullptr, Nz, Ez, INz, 0, 0, 0, 0);
  bn_stats<<<Ez, 256, 0, stream>>>(x0, bnst);
  bn_apply_pe<<<(Nz * Ez) / 256, 256, 0, stream>>>(x0, bnst, bn_g, bn_b, x, xb);
  dist_bias_k<<<Bz * Sz, 256, 0, stream>>>(distances, dist_scale, db_b);

  for (int l = 0; l < Lz; ++l) {
    // transpose layer-entry x (values for PV)
    transpose_xb<<<dim3(Sz / 32, Ez / 32, Bz), 256, 0, stream>>>(xb, xT);
    // q,k projection -> qk bf16 [N,1024]
    gemm_bt<<<dim3(1024 / 128, Nz / 128, 1), 256, 0, stream>>>(
        xb, wqk, in_proj_b, nullptr, qk, nullptr, Nz, 1024, Ez, 0, 0, 0, 0);
    attn_stats2<<<dim3(Sz / 64, Hz, Bz), 256, 0, stream>>>(qk, stats, den);
    scores_bias<<<dim3(Sz / 128, Sz / 128, Bz), 256, 0, stream>>>(qk, db_b, stats, aw, den);
    // PV: batched aw[b] @ x[b]  (values = layer-entry x), renorm by den
    gemm_bt<<<dim3(Ez / 128, Sz / 128, Bz), 256, 0, stream>>>(
        aw, xT, nullptr, aout, nullptr, den,
        Sz, Ez, Sz, (long)Sz * Sz, (long)Ez * Sz, (long)Sz * Ez, 0);
    add_ln<<<Nz, 256, 0, stream>>>(x, aout, n1_g, n1_b, x, xb);
    // FF1 (256^2 8-phase, grid 256 = full GPU)
    gemm256<<<dim3(FFz / 256, Nz / 256), 512, 0, stream>>>(
        xb, wl1, lin1_b, ff1, FFz, Ez, 1);
    gemm_bt<<<dim3(Ez / 128, Nz / 128, 1), 256, 0, stream>>>(
        ff1, wl2, lin2_b, aout, nullptr, nullptr, Nz, Ez, FFz, 0, 0, 0, 0);
    add_ln<<<Nz, 256, 0, stream>>>(x, aout, n2_g, n2_b, x, xb);
  }
}

// Round 9
// 1212.681 us; speedup vs baseline: 1.2890x; 1.2890x over previous
//
#include <hip/hip_runtime.h>
#include <hip/hip_bf16.h>
#include <math.h>

#define Bz 8
#define Sz 1024
#define INz 128
#define Ez 512
#define Hz 8
#define HDz 64
#define FFz 2048
#define Lz 4
#define Nz (Bz*Sz)   // 8192
#define EPSf 1e-5f

typedef __attribute__((ext_vector_type(8))) short short8;
typedef __attribute__((ext_vector_type(4))) float floatx4;
#define MFMA16(a,b,c) __builtin_amdgcn_mfma_f32_16x16x32_bf16(a,b,c,0,0,0)

typedef __hip_bfloat16 bf16;

__device__ inline float b2f(bf16 v) { return __bfloat162float(v); }
__device__ inline bf16 f2b(float v) { return __float2bfloat16(v); }

// async global->LDS, 16B per lane, wave-uniform LDS base (HW adds lane*16)
__device__ inline void gload16(const bf16* g, bf16* lds_base)
{
  __builtin_amdgcn_global_load_lds(
      (const __attribute__((address_space(1))) void*)g,
      (__attribute__((address_space(3))) void*)lds_base,
      16, 0, 0);
}

#define FENCE() asm volatile("" ::: "memory")
#define PB() do { FENCE(); __builtin_amdgcn_s_barrier(); FENCE(); } while (0)
#define VMCNT0() asm volatile("s_waitcnt vmcnt(0)" ::: "memory")
#define VMCNT8() asm volatile("s_waitcnt vmcnt(8)" ::: "memory")

// ---------------- fp32 -> bf16 cast
__global__ __launch_bounds__(256) void cast_f2b(const float* __restrict__ in,
    bf16* __restrict__ out, int n)
{
  int i = blockIdx.x * 256 + threadIdx.x;
  if (i < n) out[i] = f2b(in[i]);
}

// ---------------- 256x256 8-phase bf16 NT GEMM (T3+T4+T5 structure)
__global__ __launch_bounds__(512, 1) void gemm256(
    const bf16* __restrict__ A, const bf16* __restrict__ Wm,
    const float* __restrict__ bias, bf16* __restrict__ Cb,
    int N, int K, int relu)
{
  int gx = gridDim.x, nwg = gx * gridDim.y;
  int flat = blockIdx.y * gx + blockIdx.x;
  if (!(nwg & 7)) {                      // bijective chunked XCD swizzle
    int cpx = nwg >> 3;
    flat = (flat & 7) * cpx + (flat >> 3);
  }
  int bm = (flat / gx) * 256, bn = (flat % gx) * 256;
  __shared__ __align__(16) bf16 As0[256][64], Bs0[256][64];
  __shared__ __align__(16) bf16 As1[256][64], Bs1[256][64];
  int t = threadIdx.x, wave = t >> 6, lane = t & 63;
  int wm = (wave >> 2) * 128, wn = (wave & 3) * 64;
  int fr = lane & 15, fo = lane >> 4;       // fragment row / chunk group
  int w8 = wave * 8, lrow = lane >> 3;
  int sc8 = ((lane & 7) ^ (lrow & 7)) * 8;  // swizzled source col (bf16)
  floatx4 acc[8][4];
  #pragma unroll
  for (int i = 0; i < 8; ++i)
    #pragma unroll
    for (int j = 0; j < 4; ++j) acc[i][j] = (floatx4){0.f, 0.f, 0.f, 0.f};

  #define STAGE8(DA, DB, kk) do {                                           \
    _Pragma("unroll")                                                        \
    for (int c_ = 0; c_ < 4; ++c_) {                                         \
      int row_ = c_ * 64 + w8 + lrow;                                        \
      gload16(A  + (size_t)(bm + row_) * K + (kk) + sc8, &DA[c_ * 64 + w8][0]);\
      gload16(Wm + (size_t)(bn + row_) * K + (kk) + sc8, &DB[c_ * 64 + w8][0]);\
    } } while (0)

  #define TILE(AA, BB, SA, SB, kk, DOSTAGE) do {                            \
    _Pragma("unroll")                                                        \
    for (int q_ = 0; q_ < 4; ++q_) {                                         \
      short8 a_[4][2], bf_[2][2];                                            \
      _Pragma("unroll")                                                      \
      for (int j_ = 0; j_ < 4; ++j_) {                                       \
        int row_ = wm + ((q_ >> 1) * 4 + j_) * 16 + fr;                      \
        a_[j_][0] = *(const short8*)&AA[row_][((fo) ^ (fr & 7)) * 8];        \
        a_[j_][1] = *(const short8*)&AA[row_][((4 + fo) ^ (fr & 7)) * 8];    \
      }                                                                      \
      _Pragma("unroll")                                                      \
      for (int g_ = 0; g_ < 2; ++g_) {                                       \
        int row_ = wn + ((q_ & 1) * 2 + g_) * 16 + fr;                       \
        bf_[g_][0] = *(const short8*)&BB[row_][((fo) ^ (fr & 7)) * 8];       \
        bf_[g_][1] = *(const short8*)&BB[row_][((4 + fo) ^ (fr & 7)) * 8];   \
      }                                                                      \
      if ((DOSTAGE) && q_ == 0) STAGE8(SA, SB, kk);                          \
      PB();                                                                  \
      __builtin_amdgcn_s_setprio(1);                                         \
      _Pragma("unroll")                                                      \
      for (int j_ = 0; j_ < 4; ++j_)                                         \
        _Pragma("unroll")                                                    \
        for (int g_ = 0; g_ < 2; ++g_) {                                     \
          int fi_ = (q_ >> 1) * 4 + j_, gi_ = (q_ & 1) * 2 + g_;             \
          acc[fi_][gi_] = MFMA16(a_[j_][0], bf_[g_][0], acc[fi_][gi_]);      \
          acc[fi_][gi_] = MFMA16(a_[j_][1], bf_[g_][1], acc[fi_][gi_]);      \
        }                                                                    \
      __builtin_amdgcn_s_setprio(0);                                         \
      if (q_ == 3) VMCNT0();                                                 \
      PB();                                                                  \
    } } while (0)

  int nt = K >> 6;                // even, >= 2
  STAGE8(As0, Bs0, 0);
  STAGE8(As1, Bs1, 64);
  VMCNT8();                       // tile0 ready; tile1 stays in flight
  PB();
  TILE(As0, Bs0, As0, Bs0, 0, 0);                 // tile 0 (no stage)
  for (int i = 1; i + 2 < nt; i += 2) {
    TILE(As1, Bs1, As0, Bs0, (i + 1) * 64, 1);    // odd tile, stage even
    TILE(As0, Bs0, As1, Bs1, (i + 2) * 64, 1);    // even tile, stage odd
  }
  TILE(As1, Bs1, As0, Bs0, 0, 0);                 // tile nt-1 (no stage)
  #undef STAGE8
  #undef TILE

  #pragma unroll
  for (int f = 0; f < 8; ++f) {
    #pragma unroll
    for (int r = 0; r < 4; ++r) {
      int row = bm + wm + f * 16 + (lane >> 4) * 4 + r;
      #pragma unroll
      for (int g = 0; g < 4; ++g) {
        int col = bn + wn + g * 16 + fr;
        float v = acc[f][g][r] + (bias ? bias[col] : 0.f);
        if (relu) v = fmaxf(v, 0.f);
        Cb[(size_t)row * N + col] = f2b(v);
      }
    }
  }
}

// ---------------- unified bf16 MFMA NT GEMM (128x128, 2-phase dbuf)
__global__ __launch_bounds__(256) void gemm_bt(
    const bf16* __restrict__ A, const bf16* __restrict__ Wm,
    const float* __restrict__ bias, float* __restrict__ Cf,
    bf16* __restrict__ Cb, const float* __restrict__ rowscale,
    int M, int N, int K, long sA, long sW, long sC, int relu)
{
  int z = blockIdx.z;
  A  += (size_t)z * sA;
  Wm += (size_t)z * sW;
  if (rowscale) rowscale += (size_t)z * M;
  size_t cbase = (size_t)z * sC;
  int bm = blockIdx.y * 128, bn = blockIdx.x * 128;
  __shared__ __align__(16) bf16 As0[128][64], Bs0[128][64];
  __shared__ __align__(16) bf16 As1[128][64], Bs1[128][64];
  int t = threadIdx.x, wave = t >> 6, lane = t & 63;
  int wm = (wave >> 1) * 64, wn = (wave & 1) * 64;
  int fr = lane & 15, fo = lane >> 4;
  int srow = lane >> 3;
  int scol = ((lane & 7) ^ srow) * 8;
  floatx4 acc[4][4];
  #pragma unroll
  for (int i = 0; i < 4; ++i)
    #pragma unroll
    for (int j = 0; j < 4; ++j) acc[i][j] = (floatx4){0.f, 0.f, 0.f, 0.f};

  #define STAGE(Ad, Bd, kk) do {                                            \
    _Pragma("unroll")                                                        \
    for (int i_ = 0; i_ < 4; ++i_) {                                         \
      int chunk_ = wave * 4 + i_;                                            \
      int row_ = chunk_ * 8 + srow;                                          \
      gload16(A  + (size_t)(bm + row_) * K + (kk) + scol, &Ad[chunk_ * 8][0]);\
      gload16(Wm + (size_t)(bn + row_) * K + (kk) + scol, &Bd[chunk_ * 8][0]);\
    } } while (0)

  #define COMPUTE(Ad, Bd) do {                                               \
    _Pragma("unroll")                                                        \
    for (int ks_ = 0; ks_ < 2; ++ks_) {                                      \
      int sw_ = ((ks_ * 4 + fo) ^ (fr & 7)) * 8;                             \
      short8 af_[4], bf_[4];                                                 \
      _Pragma("unroll")                                                      \
      for (int rt_ = 0; rt_ < 4; ++rt_)                                      \
        af_[rt_] = *(const short8*)&Ad[wm + rt_ * 16 + fr][sw_];             \
      _Pragma("unroll")                                                      \
      for (int ct_ = 0; ct_ < 4; ++ct_)                                      \
        bf_[ct_] = *(const short8*)&Bd[wn + ct_ * 16 + fr][sw_];             \
      _Pragma("unroll")                                                      \
      for (int rt_ = 0; rt_ < 4; ++rt_)                                      \
        _Pragma("unroll")                                                    \
        for (int ct_ = 0; ct_ < 4; ++ct_)                                    \
          acc[rt_][ct_] = MFMA16(af_[rt_], bf_[ct_], acc[rt_][ct_]);         \
    } } while (0)

  STAGE(As0, Bs0, 0);
  __syncthreads();
  for (int k0 = 0; k0 < K; k0 += 128) {
    if (k0 + 64 < K) STAGE(As1, Bs1, k0 + 64);
    COMPUTE(As0, Bs0);
    __syncthreads();
    if (k0 + 64 < K) {
      if (k0 + 128 < K) STAGE(As0, Bs0, k0 + 128);
      COMPUTE(As1, Bs1);
      __syncthreads();
    }
  }
  #undef STAGE
  #undef COMPUTE

  #pragma unroll
  for (int rt = 0; rt < 4; ++rt) {
    #pragma unroll
    for (int r = 0; r < 4; ++r) {
      int row = bm + wm + rt * 16 + (lane >> 4) * 4 + r;
      float rs = rowscale ? (1.f / rowscale[row]) : 1.f;
      #pragma unroll
      for (int ct = 0; ct < 4; ++ct) {
        int col = bn + wn + ct * 16 + fr;
        float v = acc[rt][ct][r] + (bias ? bias[col] : 0.f);
        if (relu) v = fmaxf(v, 0.f);
        v *= rs;
        if (Cf) Cf[cbase + (size_t)row * N + col] = v;
        if (Cb) Cb[cbase + (size_t)row * N + col] = f2b(v);
      }
    }
  }
}

// ---------------- BatchNorm stats over N rows, per channel
__global__ __launch_bounds__(256) void bn_stats(const float* __restrict__ x, float* __restrict__ st)
{
  int c = blockIdx.x;
  float s = 0.f, q = 0.f;
  for (int r = threadIdx.x; r < Nz; r += 256) {
    float v = x[(size_t)r * Ez + c];
    s += v; q += v * v;
  }
  for (int o = 32; o; o >>= 1) { s += __shfl_down(s, o); q += __shfl_down(q, o); }
  __shared__ float shs[4], shq[4];
  int w = threadIdx.x >> 6;
  if ((threadIdx.x & 63) == 0) { shs[w] = s; shq[w] = q; }
  __syncthreads();
  if (threadIdx.x == 0) {
    s = shs[0] + shs[1] + shs[2] + shs[3];
    q = shq[0] + shq[1] + shq[2] + shq[3];
    float mu = s / (float)Nz;
    float var = q / (float)Nz - mu * mu;
    st[c] = mu;
    st[Ez + c] = rsqrtf(var + EPSf);
  }
}

// ---------------- BN apply + positional encoding -> x fp32 and xb bf16
__global__ __launch_bounds__(256) void bn_apply_pe(const float* __restrict__ x0,
    const float* __restrict__ st, const float* __restrict__ g,
    const float* __restrict__ b, float* __restrict__ x, bf16* __restrict__ xb)
{
  int idx = blockIdx.x * 256 + threadIdx.x;
  int c = idx & (Ez - 1);
  int r = idx >> 9;
  int s = r & (Sz - 1);
  float dt = expf((float)(c & ~1) * (-9.210340371976184f / (float)Ez));
  float ang = (float)s * dt;
  float pe = (c & 1) ? cosf(ang) : sinf(ang);
  float mu = st[c], rs = st[Ez + c];
  float v = (x0[idx] - mu) * rs * g[c] + b[c] + pe;
  x[idx] = v;
  xb[idx] = f2b(v);
}

// ---------------- distance bias -> bf16
__global__ __launch_bounds__(256) void dist_bias_k(const float* __restrict__ dist,
    const float* __restrict__ dsc, bf16* __restrict__ db)
{
  size_t base = (size_t)blockIdx.x * Sz;
  float m = -1e30f;
  for (int j = threadIdx.x; j < Sz; j += 256) m = fmaxf(m, dist[base + j]);
  for (int o = 32; o; o >>= 1) m = fmaxf(m, __shfl_down(m, o));
  __shared__ float sh[4];
  if ((threadIdx.x & 63) == 0) sh[threadIdx.x >> 6] = m;
  __syncthreads();
  m = fmaxf(fmaxf(sh[0], sh[1]), fmaxf(sh[2], sh[3]));
  float sc = dsc[0];
  float inv = 1.f / m;
  for (int j = threadIdx.x; j < Sz; j += 256)
    db[base + j] = f2b(expf(sc * (1.f - dist[base + j] * inv)));
}

// ---------------- transpose xb [B*S,E] -> xT [B][E][S]
__global__ __launch_bounds__(256) void transpose_xb(const bf16* __restrict__ xb,
    bf16* __restrict__ xT)
{
  int b = blockIdx.z, e0 = blockIdx.y * 32, s0 = blockIdx.x * 32;
  __shared__ bf16 T[32][40];
  int t = threadIdx.x, row = t >> 3, c = t & 7;
  *(ushort4*)&T[row][c * 4] = *(const ushort4*)(xb + (size_t)(b * Sz + s0 + row) * Ez + e0 + c * 4);
  __syncthreads();
  ushort4 v;
  unsigned short* vp = (unsigned short*)&v;
  #pragma unroll
  for (int i = 0; i < 4; ++i) vp[i] = *(const unsigned short*)&T[c * 4 + i][row];
  *(ushort4*)(xT + ((size_t)b * Ez + e0 + row) * Sz + s0 + c * 4) = v;
}

// ---------------- MFMA attention stats (R6 version): per (b,h,q) m and Z
// Also zeroes den (h==0 blocks) for scores_bias's atomic row sums.
__global__ __launch_bounds__(256) void attn_stats2(const bf16* __restrict__ qk,
    float* __restrict__ stats, float* __restrict__ den)
{
  int qt = blockIdx.x, h = blockIdx.y, b = blockIdx.z;
  int q0 = qt * 64;
  int t = threadIdx.x, wave = t >> 6, lane = t & 63;
  if (h == 0 && t < 64) den[(size_t)b * Sz + q0 + t] = 0.f;
  __shared__ bf16 Qs[64][72];
  __shared__ bf16 Ks[128][72];
  int fr = lane & 15, fo = (lane >> 4) * 8;
  #pragma unroll
  for (int i = 0; i < 2; ++i) {
    int idx = i * 256 + t, row = idx >> 3, c4 = idx & 7;
    *(float4*)&Qs[row][c4 * 8] =
      *(const float4*)(qk + (size_t)(b * Sz + q0 + row) * 1024 + h * 64 + c4 * 8);
  }
  __syncthreads();
  short8 aq0 = *(const short8*)&Qs[wave * 16 + fr][fo];
  short8 aq1 = *(const short8*)&Qs[wave * 16 + fr][32 + fo];
  float m_run[4] = {-1e30f, -1e30f, -1e30f, -1e30f};
  float z_run[4] = {0.f, 0.f, 0.f, 0.f};
  for (int k0 = 0; k0 < Sz; k0 += 128) {
    __syncthreads();
    #pragma unroll
    for (int i = 0; i < 4; ++i) {
      int idx = i * 256 + t, row = idx >> 3, c4 = idx & 7;
      *(float4*)&Ks[row][c4 * 8] =
        *(const float4*)(qk + (size_t)(b * Sz + k0 + row) * 1024 + 512 + h * 64 + c4 * 8);
    }
    __syncthreads();
    float sc[8][4];
    #pragma unroll
    for (int j = 0; j < 8; ++j) {
      floatx4 a4 = (floatx4){0.f, 0.f, 0.f, 0.f};
      short8 b0 = *(const short8*)&Ks[j * 16 + fr][fo];
      short8 b1 = *(const short8*)&Ks[j * 16 + fr][32 + fo];
      a4 = MFMA16(aq0, b0, a4);
      a4 = MFMA16(aq1, b1, a4);
      #pragma unroll
      for (int r = 0; r < 4; ++r) sc[j][r] = a4[r] * 0.125f;
    }
    #pragma unroll
    for (int r = 0; r < 4; ++r) {
      float vm = sc[0][r];
      #pragma unroll
      for (int j = 1; j < 8; ++j) vm = fmaxf(vm, sc[j][r]);
      #pragma unroll
      for (int o = 1; o < 16; o <<= 1) vm = fmaxf(vm, __shfl_xor(vm, o, 16));
      float mn = fmaxf(m_run[r], vm);
      float zb = 0.f;
      #pragma unroll
      for (int j = 0; j < 8; ++j) zb += __expf(sc[j][r] - mn);
      #pragma unroll
      for (int o = 1; o < 16; o <<= 1) zb += __shfl_xor(zb, o, 16);
      z_run[r] = z_run[r] * __expf(m_run[r] - mn) + zb;
      m_run[r] = mn;
    }
  }
  if (fr == 0) {
    int qb = q0 + wave * 16 + (lane >> 4) * 4;
    #pragma unroll
    for (int r = 0; r < 4; ++r) {
      size_t o = ((size_t)(b * Hz + h) * Sz + qb + r) * 2;
      stats[o] = m_run[r];
      stats[o + 1] = z_run[r];
    }
  }
}

// ---------------- MFMA scores: aw[b,q,k] = (1/H * sum_h softmax_h) * db (bf16)
// R6 structure (padded single-buffer LDS, per-head loop, fused rowsum) +
// T14 async-STAGE split: issue head h+1's loads to REGISTERS before
// computing head h from LDS; write regs->LDS after the post-compute
// barrier. h-loop NOT unrolled (R7 lesson: unroll -> 256 VGPR spill).
__global__ __launch_bounds__(256) void scores_bias(const bf16* __restrict__ qk,
    const bf16* __restrict__ db, const float* __restrict__ stats,
    bf16* __restrict__ aw, float* __restrict__ den)
{
  int kt = blockIdx.x, qt = blockIdx.y, b = blockIdx.z;
  int q0 = qt * 128, k0 = kt * 128;
  __shared__ bf16 Qs[128][72];
  __shared__ bf16 Ks[128][72];
  __shared__ float mS[128][9];
  __shared__ float ziS[128][9];
  int t = threadIdx.x, wave = t >> 6, lane = t & 63;
  int fr = lane & 15, fo = (lane >> 4) * 8;
  int wm = (wave >> 1) * 64, wn = (wave & 1) * 64;

  #pragma unroll
  for (int i = 0; i < 4; ++i) {
    int lin = i * 256 + t, h = lin >> 7, q = lin & 127;
    const float* sp = stats + ((size_t)(b * Hz + h) * Sz + q0 + q) * 2;
    mS[q][h] = sp[0];
    ziS[q][h] = 1.f / sp[1];
  }

  floatx4 pac[4][4];
  #pragma unroll
  for (int i = 0; i < 4; ++i)
    #pragma unroll
    for (int j = 0; j < 4; ++j) pac[i][j] = (floatx4){0.f, 0.f, 0.f, 0.f};

  float4 qreg[4], kreg[4];   // in-flight stage (32 VGPR)
  #define LDH(hh) do {                                                       \
    _Pragma("unroll")                                                        \
    for (int i_ = 0; i_ < 4; ++i_) {                                         \
      int idx_ = i_ * 256 + t, row_ = idx_ >> 3, c4_ = idx_ & 7;             \
      qreg[i_] = *(const float4*)(qk + (size_t)(b * Sz + q0 + row_) * 1024 + (hh) * 64 + c4_ * 8);      \
      kreg[i_] = *(const float4*)(qk + (size_t)(b * Sz + k0 + row_) * 1024 + 512 + (hh) * 64 + c4_ * 8);\
    } } while (0)
  #define WRH() do {                                                         \
    _Pragma("unroll")                                                        \
    for (int i_ = 0; i_ < 4; ++i_) {                                         \
      int idx_ = i_ * 256 + t, row_ = idx_ >> 3, c4_ = idx_ & 7;             \
      *(float4*)&Qs[row_][c4_ * 8] = qreg[i_];                               \
      *(float4*)&Ks[row_][c4_ * 8] = kreg[i_];                               \
    } } while (0)

  LDH(0);
  WRH();
  __syncthreads();   // LDS tile + mS/ziS ready
  for (int h = 0; h < 8; ++h) {
    if (h < 7) LDH(h + 1);          // issue-early: overlaps compute below
    short8 bfv0[4], bfv1[4];
    #pragma unroll
    for (int ct = 0; ct < 4; ++ct) {
      bfv0[ct] = *(const short8*)&Ks[wn + ct * 16 + fr][fo];
      bfv1[ct] = *(const short8*)&Ks[wn + ct * 16 + fr][32 + fo];
    }
    #pragma unroll
    for (int rt = 0; rt < 4; ++rt) {
      short8 af0 = *(const short8*)&Qs[wm + rt * 16 + fr][fo];
      short8 af1 = *(const short8*)&Qs[wm + rt * 16 + fr][32 + fo];
      floatx4 sc[4];
      #pragma unroll
      for (int ct = 0; ct < 4; ++ct) {
        floatx4 z4 = (floatx4){0.f, 0.f, 0.f, 0.f};
        z4 = MFMA16(af0, bfv0[ct], z4);
        sc[ct] = MFMA16(af1, bfv1[ct], z4);
      }
      #pragma unroll
      for (int r = 0; r < 4; ++r) {
        int qloc = wm + rt * 16 + (lane >> 4) * 4 + r;
        float m = mS[qloc][h], zi = ziS[qloc][h];
        #pragma unroll
        for (int ct = 0; ct < 4; ++ct)
          pac[rt][ct][r] += __expf(sc[ct][r] * 0.125f - m) * zi;
      }
    }
    __syncthreads();                // all lanes done reading LDS for head h
    if (h < 7) WRH();               // write-late (vmcnt wait lands here)
    __syncthreads();                // head h+1 tile visible
  }
  #undef LDH
  #undef WRH

  #pragma unroll
  for (int rt = 0; rt < 4; ++rt) {
    #pragma unroll
    for (int r = 0; r < 4; ++r) {
      int qloc = wm + rt * 16 + (lane >> 4) * 4 + r;
      size_t rowoff = (size_t)(b * Sz + q0 + qloc) * Sz + k0;
      float rsum = 0.f;
      #pragma unroll
      for (int ct = 0; ct < 4; ++ct) {
        int kloc = wn + ct * 16 + fr;
        float p = pac[rt][ct][r] * 0.125f * b2f(db[rowoff + kloc]);
        aw[rowoff + kloc] = f2b(p);
        rsum += p;
      }
      #pragma unroll
      for (int o = 1; o < 16; o <<= 1) rsum += __shfl_xor(rsum, o, 16);
      if (fr == 0) atomicAdd(den + (size_t)b * Sz + q0 + qloc, rsum);
    }
  }
}

// ---------------- residual add + LayerNorm -> x fp32, xb bf16 (float2 vec)
__global__ __launch_bounds__(256) void add_ln(const float* __restrict__ xin,
    const float* __restrict__ dly, const float* __restrict__ g,
    const float* __restrict__ bb, float* __restrict__ xout, bf16* __restrict__ xbout)
{
  size_t base = (size_t)blockIdx.x * Ez;
  int t = threadIdx.x;
  float2 xi = *(const float2*)(xin + base + t * 2);
  float2 dl = *(const float2*)(dly + base + t * 2);
  float a0 = xi.x + dl.x;
  float a1 = xi.y + dl.y;
  float s = a0 + a1, q = a0 * a0 + a1 * a1;
  for (int o = 32; o; o >>= 1) { s += __shfl_down(s, o); q += __shfl_down(q, o); }
  __shared__ float shs[4], shq[4];
  if ((t & 63) == 0) { shs[t >> 6] = s; shq[t >> 6] = q; }
  __syncthreads();
  s = shs[0] + shs[1] + shs[2] + shs[3];
  q = shq[0] + shq[1] + shq[2] + shq[3];
  float mu = s * (1.f / Ez);
  float var = q * (1.f / Ez) - mu * mu;
  float rs = rsqrtf(var + EPSf);
  float v0 = (a0 - mu) * rs * g[t * 2] + bb[t * 2];
  float v1 = (a1 - mu) * rs * g[t * 2 + 1] + bb[t * 2 + 1];
  float2 vo; vo.x = v0; vo.y = v1;
  *(float2*)(xout + base + t * 2) = vo;
  bf16 b0 = f2b(v0), b1 = f2b(v1);
  ushort2 pk;
  pk.x = *(unsigned short*)&b0;
  pk.y = *(unsigned short*)&b1;
  *(ushort2*)(xbout + base + t * 2) = pk;
}

extern "C" void kernel_launch(void* const* d_in, const int* in_sizes, int n_in,
                              void* d_out, int out_size, void* d_ws, size_t ws_size,
                              hipStream_t stream)
{
  const float* src        = (const float*)d_in[0];
  const float* distances  = (const float*)d_in[1];
  const float* proj_w     = (const float*)d_in[2];
  const float* proj_b     = (const float*)d_in[3];
  const float* bn_g       = (const float*)d_in[4];
  const float* bn_b       = (const float*)d_in[5];
  const float* in_proj_w  = (const float*)d_in[6];
  const float* in_proj_b  = (const float*)d_in[7];
  const float* dist_scale = (const float*)d_in[8];
  const float* lin1_w     = (const float*)d_in[9];
  const float* lin1_b     = (const float*)d_in[10];
  const float* lin2_w     = (const float*)d_in[11];
  const float* lin2_b     = (const float*)d_in[12];
  const float* n1_g       = (const float*)d_in[13];
  const float* n1_b       = (const float*)d_in[14];
  const float* n2_g       = (const float*)d_in[15];
  const float* n2_b       = (const float*)d_in[16];

  float* x = (float*)d_out;                      // fp32 activations [N,E]

  // workspace layout (≈88 MB)
  float* stats = (float*)d_ws;                   // B*H*S*2
  float* den   = stats + 131072;                 // B*S
  float* bnst  = den + 8192;                     // 2*E
  float* aout  = bnst + 1024;                    // N*E fp32
  float* x0    = aout;                           // alias (pre-loop only)
  bf16* db_b = (bf16*)(aout + (size_t)Nz * Ez);  // B*S*S
  bf16* Rqk  = db_b + (size_t)Bz * Sz * Sz;      // union region: qk+aw | ff1
  bf16* qk   = Rqk;                              // N*1024
  bf16* aw   = Rqk + (size_t)Nz * 1024;          // B*S*S
  bf16* ff1  = Rqk;                              // N*FF (aliases qk+aw, disjoint lifetime)
  bf16* xb   = Rqk + (size_t)Nz * FFz;           // N*E
  bf16* xT   = xb + (size_t)Nz * Ez;             // B*E*S
  bf16* srcb = xT + (size_t)Bz * Ez * Sz;        // N*IN
  bf16* wpr  = srcb + (size_t)Nz * INz;          // E*IN
  bf16* wqk  = wpr + Ez * INz;                   // 1024*E (q,k rows only)
  bf16* wl1  = wqk + 1024 * Ez;                  // FF*E
  bf16* wl2  = wl1 + FFz * Ez;                   // E*FF

  // weight / input casts
  cast_f2b<<<(Nz * INz) / 256, 256, 0, stream>>>(src, srcb, Nz * INz);
  cast_f2b<<<(Ez * INz + 255) / 256, 256, 0, stream>>>(proj_w, wpr, Ez * INz);
  cast_f2b<<<(1024 * Ez) / 256, 256, 0, stream>>>(in_proj_w, wqk, 1024 * Ez);
  cast_f2b<<<(FFz * Ez) / 256, 256, 0, stream>>>(lin1_w, wl1, FFz * Ez);
  cast_f2b<<<(Ez * FFz) / 256, 256, 0, stream>>>(lin2_w, wl2, Ez * FFz);

  // input projection -> x0 fp32
  gemm_bt<<<dim3(Ez / 128, Nz / 128, 1), 256, 0, stream>>>(
      srcb, wpr, proj_b, x0, nullptr, nullptr, Nz, Ez, INz, 0, 0, 0, 0);
  bn_stats<<<Ez, 256, 0, stream>>>(x0, bnst);
  bn_apply_pe<<<(Nz * Ez) / 256, 256, 0, stream>>>(x0, bnst, bn_g, bn_b, x, xb);
  dist_bias_k<<<Bz * Sz, 256, 0, stream>>>(distances, dist_scale, db_b);

  for (int l = 0; l < Lz; ++l) {
    // transpose layer-entry x (values for PV)
    transpose_xb<<<dim3(Sz / 32, Ez / 32, Bz), 256, 0, stream>>>(xb, xT);
    // q,k projection -> qk bf16 [N,1024]
    gemm_bt<<<dim3(1024 / 128, Nz / 128, 1), 256, 0, stream>>>(
        xb, wqk, in_proj_b, nullptr, qk, nullptr, Nz, 1024, Ez, 0, 0, 0, 0);
    attn_stats2<<<dim3(Sz / 64, Hz, Bz), 256, 0, stream>>>(qk, stats, den);
    scores_bias<<<dim3(Sz / 128, Sz / 128, Bz), 256, 0, stream>>>(qk, db_b, stats, aw, den);
    // PV: batched aw[b] @ x[b]  (values = layer-entry x), renorm by den
    gemm_bt<<<dim3(Ez / 128, Sz / 128, Bz), 256, 0, stream>>>(
        aw, xT, nullptr, aout, nullptr, den,
        Sz, Ez, Sz, (long)Sz * Sz, (long)Ez * Sz, (long)Sz * Ez, 0);
    add_ln<<<Nz, 256, 0, stream>>>(x, aout, n1_g, n1_b, x, xb);
    // FF1 (256^2 8-phase, grid 256 = full GPU)
    gemm256<<<dim3(FFz / 256, Nz / 256), 512, 0, stream>>>(
        xb, wl1, lin1_b, ff1, FFz, Ez, 1);
    gemm_bt<<<dim3(Ez / 128, Nz / 128, 1), 256, 0, stream>>>(
        ff1, wl2, lin2_b, aout, nullptr, nullptr, Nz, Ez, FFz, 0, 0, 0, 0);
    add_ln<<<Nz, 256, 0, stream>>>(x, aout, n2_g, n2_b, x, xb);
  }
}

// Round 10
// 1124.432 us; speedup vs baseline: 1.3901x; 1.0785x over previous
//
#include <hip/hip_runtime.h>
#include <hip/hip_bf16.h>
#include <math.h>

#define Bz 8
#define Sz 1024
#define INz 128
#define Ez 512
#define Hz 8
#define HDz 64
#define FFz 2048
#define Lz 4
#define Nz (Bz*Sz)   // 8192
#define EPSf 1e-5f

typedef __attribute__((ext_vector_type(8))) short short8;
typedef __attribute__((ext_vector_type(4))) float floatx4;
#define MFMA16(a,b,c) __builtin_amdgcn_mfma_f32_16x16x32_bf16(a,b,c,0,0,0)

typedef __hip_bfloat16 bf16;

__device__ inline float b2f(bf16 v) { return __bfloat162float(v); }
__device__ inline bf16 f2b(float v) { return __float2bfloat16(v); }

// async global->LDS, 16B per lane, wave-uniform LDS base (HW adds lane*16)
__device__ inline void gload16(const bf16* g, bf16* lds_base)
{
  __builtin_amdgcn_global_load_lds(
      (const __attribute__((address_space(1))) void*)g,
      (__attribute__((address_space(3))) void*)lds_base,
      16, 0, 0);
}

#define FENCE() asm volatile("" ::: "memory")
#define PB() do { FENCE(); __builtin_amdgcn_s_barrier(); FENCE(); } while (0)
#define VMCNT0() asm volatile("s_waitcnt vmcnt(0)" ::: "memory")
#define VMCNT8() asm volatile("s_waitcnt vmcnt(8)" ::: "memory")

// ---------------- fp32 -> bf16 cast
__global__ __launch_bounds__(256) void cast_f2b(const float* __restrict__ in,
    bf16* __restrict__ out, int n)
{
  int i = blockIdx.x * 256 + threadIdx.x;
  if (i < n) out[i] = f2b(in[i]);
}

// ---------------- 256x256 8-phase bf16 NT GEMM (T3+T4+T5 structure)
__global__ __launch_bounds__(512, 1) void gemm256(
    const bf16* __restrict__ A, const bf16* __restrict__ Wm,
    const float* __restrict__ bias, bf16* __restrict__ Cb,
    int N, int K, int relu)
{
  int gx = gridDim.x, nwg = gx * gridDim.y;
  int flat = blockIdx.y * gx + blockIdx.x;
  if (!(nwg & 7)) {                      // bijective chunked XCD swizzle
    int cpx = nwg >> 3;
    flat = (flat & 7) * cpx + (flat >> 3);
  }
  int bm = (flat / gx) * 256, bn = (flat % gx) * 256;
  __shared__ __align__(16) bf16 As0[256][64], Bs0[256][64];
  __shared__ __align__(16) bf16 As1[256][64], Bs1[256][64];
  int t = threadIdx.x, wave = t >> 6, lane = t & 63;
  int wm = (wave >> 2) * 128, wn = (wave & 3) * 64;
  int fr = lane & 15, fo = lane >> 4;       // fragment row / chunk group
  int w8 = wave * 8, lrow = lane >> 3;
  int sc8 = ((lane & 7) ^ (lrow & 7)) * 8;  // swizzled source col (bf16)
  floatx4 acc[8][4];
  #pragma unroll
  for (int i = 0; i < 8; ++i)
    #pragma unroll
    for (int j = 0; j < 4; ++j) acc[i][j] = (floatx4){0.f, 0.f, 0.f, 0.f};

  #define STAGE8(DA, DB, kk) do {                                           \
    _Pragma("unroll")                                                        \
    for (int c_ = 0; c_ < 4; ++c_) {                                         \
      int row_ = c_ * 64 + w8 + lrow;                                        \
      gload16(A  + (size_t)(bm + row_) * K + (kk) + sc8, &DA[c_ * 64 + w8][0]);\
      gload16(Wm + (size_t)(bn + row_) * K + (kk) + sc8, &DB[c_ * 64 + w8][0]);\
    } } while (0)

  #define TILE(AA, BB, SA, SB, kk, DOSTAGE) do {                            \
    _Pragma("unroll")                                                        \
    for (int q_ = 0; q_ < 4; ++q_) {                                         \
      short8 a_[4][2], bf_[2][2];                                            \
      _Pragma("unroll")                                                      \
      for (int j_ = 0; j_ < 4; ++j_) {                                       \
        int row_ = wm + ((q_ >> 1) * 4 + j_) * 16 + fr;                      \
        a_[j_][0] = *(const short8*)&AA[row_][((fo) ^ (fr & 7)) * 8];        \
        a_[j_][1] = *(const short8*)&AA[row_][((4 + fo) ^ (fr & 7)) * 8];    \
      }                                                                      \
      _Pragma("unroll")                                                      \
      for (int g_ = 0; g_ < 2; ++g_) {                                       \
        int row_ = wn + ((q_ & 1) * 2 + g_) * 16 + fr;                       \
        bf_[g_][0] = *(const short8*)&BB[row_][((fo) ^ (fr & 7)) * 8];       \
        bf_[g_][1] = *(const short8*)&BB[row_][((4 + fo) ^ (fr & 7)) * 8];   \
      }                                                                      \
      if ((DOSTAGE) && q_ == 0) STAGE8(SA, SB, kk);                          \
      PB();                                                                  \
      __builtin_amdgcn_s_setprio(1);                                         \
      _Pragma("unroll")                                                      \
      for (int j_ = 0; j_ < 4; ++j_)                                         \
        _Pragma("unroll")                                                    \
        for (int g_ = 0; g_ < 2; ++g_) {                                     \
          int fi_ = (q_ >> 1) * 4 + j_, gi_ = (q_ & 1) * 2 + g_;             \
          acc[fi_][gi_] = MFMA16(a_[j_][0], bf_[g_][0], acc[fi_][gi_]);      \
          acc[fi_][gi_] = MFMA16(a_[j_][1], bf_[g_][1], acc[fi_][gi_]);      \
        }                                                                    \
      __builtin_amdgcn_s_setprio(0);                                         \
      if (q_ == 3) VMCNT0();                                                 \
      PB();                                                                  \
    } } while (0)

  int nt = K >> 6;                // even, >= 2
  STAGE8(As0, Bs0, 0);
  STAGE8(As1, Bs1, 64);
  VMCNT8();                       // tile0 ready; tile1 stays in flight
  PB();
  TILE(As0, Bs0, As0, Bs0, 0, 0);                 // tile 0 (no stage)
  for (int i = 1; i + 2 < nt; i += 2) {
    TILE(As1, Bs1, As0, Bs0, (i + 1) * 64, 1);    // odd tile, stage even
    TILE(As0, Bs0, As1, Bs1, (i + 2) * 64, 1);    // even tile, stage odd
  }
  TILE(As1, Bs1, As0, Bs0, 0, 0);                 // tile nt-1 (no stage)
  #undef STAGE8
  #undef TILE

  #pragma unroll
  for (int f = 0; f < 8; ++f) {
    #pragma unroll
    for (int r = 0; r < 4; ++r) {
      int row = bm + wm + f * 16 + (lane >> 4) * 4 + r;
      #pragma unroll
      for (int g = 0; g < 4; ++g) {
        int col = bn + wn + g * 16 + fr;
        float v = acc[f][g][r] + (bias ? bias[col] : 0.f);
        if (relu) v = fmaxf(v, 0.f);
        Cb[(size_t)row * N + col] = f2b(v);
      }
    }
  }
}

// ---------------- unified bf16 MFMA NT GEMM (128x128, 2-phase dbuf)
__global__ __launch_bounds__(256) void gemm_bt(
    const bf16* __restrict__ A, const bf16* __restrict__ Wm,
    const float* __restrict__ bias, float* __restrict__ Cf,
    bf16* __restrict__ Cb, const float* __restrict__ rowscale,
    int M, int N, int K, long sA, long sW, long sC, int relu)
{
  int z = blockIdx.z;
  A  += (size_t)z * sA;
  Wm += (size_t)z * sW;
  if (rowscale) rowscale += (size_t)z * M;
  size_t cbase = (size_t)z * sC;
  int bm = blockIdx.y * 128, bn = blockIdx.x * 128;
  __shared__ __align__(16) bf16 As0[128][64], Bs0[128][64];
  __shared__ __align__(16) bf16 As1[128][64], Bs1[128][64];
  int t = threadIdx.x, wave = t >> 6, lane = t & 63;
  int wm = (wave >> 1) * 64, wn = (wave & 1) * 64;
  int fr = lane & 15, fo = lane >> 4;
  int srow = lane >> 3;
  int scol = ((lane & 7) ^ srow) * 8;
  floatx4 acc[4][4];
  #pragma unroll
  for (int i = 0; i < 4; ++i)
    #pragma unroll
    for (int j = 0; j < 4; ++j) acc[i][j] = (floatx4){0.f, 0.f, 0.f, 0.f};

  #define STAGE(Ad, Bd, kk) do {                                            \
    _Pragma("unroll")                                                        \
    for (int i_ = 0; i_ < 4; ++i_) {                                         \
      int chunk_ = wave * 4 + i_;                                            \
      int row_ = chunk_ * 8 + srow;                                          \
      gload16(A  + (size_t)(bm + row_) * K + (kk) + scol, &Ad[chunk_ * 8][0]);\
      gload16(Wm + (size_t)(bn + row_) * K + (kk) + scol, &Bd[chunk_ * 8][0]);\
    } } while (0)

  #define COMPUTE(Ad, Bd) do {                                               \
    _Pragma("unroll")                                                        \
    for (int ks_ = 0; ks_ < 2; ++ks_) {                                      \
      int sw_ = ((ks_ * 4 + fo) ^ (fr & 7)) * 8;                             \
      short8 af_[4], bf_[4];                                                 \
      _Pragma("unroll")                                                      \
      for (int rt_ = 0; rt_ < 4; ++rt_)                                      \
        af_[rt_] = *(const short8*)&Ad[wm + rt_ * 16 + fr][sw_];             \
      _Pragma("unroll")                                                      \
      for (int ct_ = 0; ct_ < 4; ++ct_)                                      \
        bf_[ct_] = *(const short8*)&Bd[wn + ct_ * 16 + fr][sw_];             \
      _Pragma("unroll")                                                      \
      for (int rt_ = 0; rt_ < 4; ++rt_)                                      \
        _Pragma("unroll")                                                    \
        for (int ct_ = 0; ct_ < 4; ++ct_)                                    \
          acc[rt_][ct_] = MFMA16(af_[rt_], bf_[ct_], acc[rt_][ct_]);         \
    } } while (0)

  STAGE(As0, Bs0, 0);
  __syncthreads();
  for (int k0 = 0; k0 < K; k0 += 128) {
    if (k0 + 64 < K) STAGE(As1, Bs1, k0 + 64);
    COMPUTE(As0, Bs0);
    __syncthreads();
    if (k0 + 64 < K) {
      if (k0 + 128 < K) STAGE(As0, Bs0, k0 + 128);
      COMPUTE(As1, Bs1);
      __syncthreads();
    }
  }
  #undef STAGE
  #undef COMPUTE

  #pragma unroll
  for (int rt = 0; rt < 4; ++rt) {
    #pragma unroll
    for (int r = 0; r < 4; ++r) {
      int row = bm + wm + rt * 16 + (lane >> 4) * 4 + r;
      float rs = rowscale ? (1.f / rowscale[row]) : 1.f;
      #pragma unroll
      for (int ct = 0; ct < 4; ++ct) {
        int col = bn + wn + ct * 16 + fr;
        float v = acc[rt][ct][r] + (bias ? bias[col] : 0.f);
        if (relu) v = fmaxf(v, 0.f);
        v *= rs;
        if (Cf) Cf[cbase + (size_t)row * N + col] = v;
        if (Cb) Cb[cbase + (size_t)row * N + col] = f2b(v);
      }
    }
  }
}

// ---------------- BatchNorm stats over N rows, per channel
__global__ __launch_bounds__(256) void bn_stats(const float* __restrict__ x, float* __restrict__ st)
{
  int c = blockIdx.x;
  float s = 0.f, q = 0.f;
  for (int r = threadIdx.x; r < Nz; r += 256) {
    float v = x[(size_t)r * Ez + c];
    s += v; q += v * v;
  }
  for (int o = 32; o; o >>= 1) { s += __shfl_down(s, o); q += __shfl_down(q, o); }
  __shared__ float shs[4], shq[4];
  int w = threadIdx.x >> 6;
  if ((threadIdx.x & 63) == 0) { shs[w] = s; shq[w] = q; }
  __syncthreads();
  if (threadIdx.x == 0) {
    s = shs[0] + shs[1] + shs[2] + shs[3];
    q = shq[0] + shq[1] + shq[2] + shq[3];
    float mu = s / (float)Nz;
    float var = q / (float)Nz - mu * mu;
    st[c] = mu;
    st[Ez + c] = rsqrtf(var + EPSf);
  }
}

// ---------------- BN apply + positional encoding -> x fp32 and xb bf16
__global__ __launch_bounds__(256) void bn_apply_pe(const float* __restrict__ x0,
    const float* __restrict__ st, const float* __restrict__ g,
    const float* __restrict__ b, float* __restrict__ x, bf16* __restrict__ xb)
{
  int idx = blockIdx.x * 256 + threadIdx.x;
  int c = idx & (Ez - 1);
  int r = idx >> 9;
  int s = r & (Sz - 1);
  float dt = expf((float)(c & ~1) * (-9.210340371976184f / (float)Ez));
  float ang = (float)s * dt;
  float pe = (c & 1) ? cosf(ang) : sinf(ang);
  float mu = st[c], rs = st[Ez + c];
  float v = (x0[idx] - mu) * rs * g[c] + b[c] + pe;
  x[idx] = v;
  xb[idx] = f2b(v);
}

// ---------------- distance bias -> bf16
__global__ __launch_bounds__(256) void dist_bias_k(const float* __restrict__ dist,
    const float* __restrict__ dsc, bf16* __restrict__ db)
{
  size_t base = (size_t)blockIdx.x * Sz;
  float m = -1e30f;
  for (int j = threadIdx.x; j < Sz; j += 256) m = fmaxf(m, dist[base + j]);
  for (int o = 32; o; o >>= 1) m = fmaxf(m, __shfl_down(m, o));
  __shared__ float sh[4];
  if ((threadIdx.x & 63) == 0) sh[threadIdx.x >> 6] = m;
  __syncthreads();
  m = fmaxf(fmaxf(sh[0], sh[1]), fmaxf(sh[2], sh[3]));
  float sc = dsc[0];
  float inv = 1.f / m;
  for (int j = threadIdx.x; j < Sz; j += 256)
    db[base + j] = f2b(expf(sc * (1.f - dist[base + j] * inv)));
}

// ---------------- transpose xb [B*S,E] -> xT [B][E][S]
__global__ __launch_bounds__(256) void transpose_xb(const bf16* __restrict__ xb,
    bf16* __restrict__ xT)
{
  int b = blockIdx.z, e0 = blockIdx.y * 32, s0 = blockIdx.x * 32;
  __shared__ bf16 T[32][40];
  int t = threadIdx.x, row = t >> 3, c = t & 7;
  *(ushort4*)&T[row][c * 4] = *(const ushort4*)(xb + (size_t)(b * Sz + s0 + row) * Ez + e0 + c * 4);
  __syncthreads();
  ushort4 v;
  unsigned short* vp = (unsigned short*)&v;
  #pragma unroll
  for (int i = 0; i < 4; ++i) vp[i] = *(const unsigned short*)&T[c * 4 + i][row];
  *(ushort4*)(xT + ((size_t)b * Ez + e0 + row) * Sz + s0 + c * 4) = v;
}

// ---------------- MFMA attention stats (R6 version): per (b,h,q) m and Z
// Also zeroes den (h==0 blocks) for scores_bias's atomic row sums.
__global__ __launch_bounds__(256) void attn_stats2(const bf16* __restrict__ qk,
    float* __restrict__ stats, float* __restrict__ den)
{
  int qt = blockIdx.x, h = blockIdx.y, b = blockIdx.z;
  int q0 = qt * 64;
  int t = threadIdx.x, wave = t >> 6, lane = t & 63;
  if (h == 0 && t < 64) den[(size_t)b * Sz + q0 + t] = 0.f;
  __shared__ bf16 Qs[64][72];
  __shared__ bf16 Ks[128][72];
  int fr = lane & 15, fo = (lane >> 4) * 8;
  #pragma unroll
  for (int i = 0; i < 2; ++i) {
    int idx = i * 256 + t, row = idx >> 3, c4 = idx & 7;
    *(float4*)&Qs[row][c4 * 8] =
      *(const float4*)(qk + (size_t)(b * Sz + q0 + row) * 1024 + h * 64 + c4 * 8);
  }
  __syncthreads();
  short8 aq0 = *(const short8*)&Qs[wave * 16 + fr][fo];
  short8 aq1 = *(const short8*)&Qs[wave * 16 + fr][32 + fo];
  float m_run[4] = {-1e30f, -1e30f, -1e30f, -1e30f};
  float z_run[4] = {0.f, 0.f, 0.f, 0.f};
  for (int k0 = 0; k0 < Sz; k0 += 128) {
    __syncthreads();
    #pragma unroll
    for (int i = 0; i < 4; ++i) {
      int idx = i * 256 + t, row = idx >> 3, c4 = idx & 7;
      *(float4*)&Ks[row][c4 * 8] =
        *(const float4*)(qk + (size_t)(b * Sz + k0 + row) * 1024 + 512 + h * 64 + c4 * 8);
    }
    __syncthreads();
    float sc[8][4];
    #pragma unroll
    for (int j = 0; j < 8; ++j) {
      floatx4 a4 = (floatx4){0.f, 0.f, 0.f, 0.f};
      short8 b0 = *(const short8*)&Ks[j * 16 + fr][fo];
      short8 b1 = *(const short8*)&Ks[j * 16 + fr][32 + fo];
      a4 = MFMA16(aq0, b0, a4);
      a4 = MFMA16(aq1, b1, a4);
      #pragma unroll
      for (int r = 0; r < 4; ++r) sc[j][r] = a4[r] * 0.125f;
    }
    #pragma unroll
    for (int r = 0; r < 4; ++r) {
      float vm = sc[0][r];
      #pragma unroll
      for (int j = 1; j < 8; ++j) vm = fmaxf(vm, sc[j][r]);
      #pragma unroll
      for (int o = 1; o < 16; o <<= 1) vm = fmaxf(vm, __shfl_xor(vm, o, 16));
      float mn = fmaxf(m_run[r], vm);
      float zb = 0.f;
      #pragma unroll
      for (int j = 0; j < 8; ++j) zb += __expf(sc[j][r] - mn);
      #pragma unroll
      for (int o = 1; o < 16; o <<= 1) zb += __shfl_xor(zb, o, 16);
      z_run[r] = z_run[r] * __expf(m_run[r] - mn) + zb;
      m_run[r] = mn;
    }
  }
  if (fr == 0) {
    int qb = q0 + wave * 16 + (lane >> 4) * 4;
    #pragma unroll
    for (int r = 0; r < 4; ++r) {
      size_t o = ((size_t)(b * Hz + h) * Sz + qb + r) * 2;
      stats[o] = m_run[r];
      stats[o + 1] = z_run[r];
    }
  }
}

// ---------------- MFMA scores: aw[b,q,k] = (1/H * sum_h softmax_h) * db (bf16)
// gload16 double-buffered per-head pipeline (async DMA -> LDS; data never
// in VGPRs, so no spill — R9's reg-staged T14 spilled qreg/kreg at the
// barrier, +120 MB scratch). h-loop unroll 1 (R7 lesson: full unroll ->
// 256 VGPR). Linear LDS + involution swizzle (verified 0-conflict, R4).
// + fused row-sum via wave reduce + atomicAdd -> den.
__global__ __launch_bounds__(256) void scores_bias(const bf16* __restrict__ qk,
    const bf16* __restrict__ db, const float* __restrict__ stats,
    bf16* __restrict__ aw, float* __restrict__ den)
{
  int kt = blockIdx.x, qt = blockIdx.y, b = blockIdx.z;
  int q0 = qt * 128, k0 = kt * 128;
  __shared__ __align__(16) bf16 Qs0[128][64], Ks0[128][64];
  __shared__ __align__(16) bf16 Qs1[128][64], Ks1[128][64];
  __shared__ float mS[128][9];
  __shared__ float ziS[128][9];
  int t = threadIdx.x, wave = t >> 6, lane = t & 63;
  int fr = lane & 15, fo = lane >> 4;
  int wm = (wave >> 1) * 64, wn = (wave & 1) * 64;
  int srow = lane >> 3;
  int scol = ((lane & 7) ^ srow) * 8;
  int sw0 = ((fo) ^ (fr & 7)) * 8, sw1 = ((4 + fo) ^ (fr & 7)) * 8;

  #pragma unroll
  for (int i = 0; i < 4; ++i) {
    int lin = i * 256 + t, h = lin >> 7, q = lin & 127;
    const float* sp = stats + ((size_t)(b * Hz + h) * Sz + q0 + q) * 2;
    mS[q][h] = sp[0];
    ziS[q][h] = 1.f / sp[1];
  }

  floatx4 pac[4][4];
  #pragma unroll
  for (int i = 0; i < 4; ++i)
    #pragma unroll
    for (int j = 0; j < 4; ++j) pac[i][j] = (floatx4){0.f, 0.f, 0.f, 0.f};

  #define STAGEH(Qd, Kd, hh) do {                                            \
    _Pragma("unroll")                                                        \
    for (int i_ = 0; i_ < 4; ++i_) {                                         \
      int chunk_ = wave * 4 + i_, row_ = chunk_ * 8 + srow;                  \
      gload16(qk + (size_t)(b * Sz + q0 + row_) * 1024 + (hh) * 64 + scol,   \
              &Qd[chunk_ * 8][0]);                                           \
      gload16(qk + (size_t)(b * Sz + k0 + row_) * 1024 + 512 + (hh) * 64 + scol,\
              &Kd[chunk_ * 8][0]);                                           \
    } } while (0)

  #define HCOMP(Qd, Kd, hh) do {                                             \
    short8 bfv0[4], bfv1[4];                                                 \
    _Pragma("unroll")                                                        \
    for (int ct = 0; ct < 4; ++ct) {                                         \
      bfv0[ct] = *(const short8*)&Kd[wn + ct * 16 + fr][sw0];                \
      bfv1[ct] = *(const short8*)&Kd[wn + ct * 16 + fr][sw1];                \
    }                                                                        \
    _Pragma("unroll")                                                        \
    for (int rt = 0; rt < 4; ++rt) {                                         \
      short8 af0 = *(const short8*)&Qd[wm + rt * 16 + fr][sw0];              \
      short8 af1 = *(const short8*)&Qd[wm + rt * 16 + fr][sw1];              \
      floatx4 sc[4];                                                         \
      _Pragma("unroll")                                                      \
      for (int ct = 0; ct < 4; ++ct) {                                       \
        floatx4 z4 = (floatx4){0.f, 0.f, 0.f, 0.f};                          \
        z4 = MFMA16(af0, bfv0[ct], z4);                                      \
        sc[ct] = MFMA16(af1, bfv1[ct], z4);                                  \
      }                                                                      \
      _Pragma("unroll")                                                      \
      for (int r = 0; r < 4; ++r) {                                          \
        int qloc = wm + rt * 16 + (lane >> 4) * 4 + r;                       \
        float m = mS[qloc][hh], zi = ziS[qloc][hh];                          \
        _Pragma("unroll")                                                    \
        for (int ct = 0; ct < 4; ++ct)                                       \
          pac[rt][ct][r] += __expf(sc[ct][r] * 0.125f - m) * zi;             \
      }                                                                      \
    } } while (0)

  STAGEH(Qs0, Ks0, 0);
  __syncthreads();   // drains gload16 -> tile0 ready; also covers mS/ziS
  #pragma unroll 1
  for (int h = 0; h < 8; h += 2) {
    STAGEH(Qs1, Ks1, h + 1);          // async prefetch overlaps compute
    HCOMP(Qs0, Ks0, h);
    __syncthreads();                  // drains -> buf1 ready; buf0 free
    if (h + 2 < 8) STAGEH(Qs0, Ks0, h + 2);
    HCOMP(Qs1, Ks1, h + 1);
    __syncthreads();                  // drains -> buf0 ready; buf1 free
  }
  #undef STAGEH
  #undef HCOMP

  #pragma unroll
  for (int rt = 0; rt < 4; ++rt) {
    #pragma unroll
    for (int r = 0; r < 4; ++r) {
      int qloc = wm + rt * 16 + (lane >> 4) * 4 + r;
      size_t rowoff = (size_t)(b * Sz + q0 + qloc) * Sz + k0;
      float rsum = 0.f;
      #pragma unroll
      for (int ct = 0; ct < 4; ++ct) {
        int kloc = wn + ct * 16 + fr;
        float p = pac[rt][ct][r] * 0.125f * b2f(db[rowoff + kloc]);
        aw[rowoff + kloc] = f2b(p);
        rsum += p;
      }
      #pragma unroll
      for (int o = 1; o < 16; o <<= 1) rsum += __shfl_xor(rsum, o, 16);
      if (fr == 0) atomicAdd(den + (size_t)b * Sz + q0 + qloc, rsum);
    }
  }
}

// ---------------- residual add + LayerNorm -> x fp32, xb bf16 (float2 vec)
__global__ __launch_bounds__(256) void add_ln(const float* __restrict__ xin,
    const float* __restrict__ dly, const float* __restrict__ g,
    const float* __restrict__ bb, float* __restrict__ xout, bf16* __restrict__ xbout)
{
  size_t base = (size_t)blockIdx.x * Ez;
  int t = threadIdx.x;
  float2 xi = *(const float2*)(xin + base + t * 2);
  float2 dl = *(const float2*)(dly + base + t * 2);
  float a0 = xi.x + dl.x;
  float a1 = xi.y + dl.y;
  float s = a0 + a1, q = a0 * a0 + a1 * a1;
  for (int o = 32; o; o >>= 1) { s += __shfl_down(s, o); q += __shfl_down(q, o); }
  __shared__ float shs[4], shq[4];
  if ((t & 63) == 0) { shs[t >> 6] = s; shq[t >> 6] = q; }
  __syncthreads();
  s = shs[0] + shs[1] + shs[2] + shs[3];
  q = shq[0] + shq[1] + shq[2] + shq[3];
  float mu = s * (1.f / Ez);
  float var = q * (1.f / Ez) - mu * mu;
  float rs = rsqrtf(var + EPSf);
  float v0 = (a0 - mu) * rs * g[t * 2] + bb[t * 2];
  float v1 = (a1 - mu) * rs * g[t * 2 + 1] + bb[t * 2 + 1];
  float2 vo; vo.x = v0; vo.y = v1;
  *(float2*)(xout + base + t * 2) = vo;
  bf16 b0 = f2b(v0), b1 = f2b(v1);
  ushort2 pk;
  pk.x = *(unsigned short*)&b0;
  pk.y = *(unsigned short*)&b1;
  *(ushort2*)(xbout + base + t * 2) = pk;
}

extern "C" void kernel_launch(void* const* d_in, const int* in_sizes, int n_in,
                              void* d_out, int out_size, void* d_ws, size_t ws_size,
                              hipStream_t stream)
{
  const float* src        = (const float*)d_in[0];
  const float* distances  = (const float*)d_in[1];
  const float* proj_w     = (const float*)d_in[2];
  const float* proj_b     = (const float*)d_in[3];
  const float* bn_g       = (const float*)d_in[4];
  const float* bn_b       = (const float*)d_in[5];
  const float* in_proj_w  = (const float*)d_in[6];
  const float* in_proj_b  = (const float*)d_in[7];
  const float* dist_scale = (const float*)d_in[8];
  const float* lin1_w     = (const float*)d_in[9];
  const float* lin1_b     = (const float*)d_in[10];
  const float* lin2_w     = (const float*)d_in[11];
  const float* lin2_b     = (const float*)d_in[12];
  const float* n1_g       = (const float*)d_in[13];
  const float* n1_b       = (const float*)d_in[14];
  const float* n2_g       = (const float*)d_in[15];
  const float* n2_b       = (const float*)d_in[16];

  float* x = (float*)d_out;                      // fp32 activations [N,E]

  // workspace layout (≈88 MB)
  float* stats = (float*)d_ws;                   // B*H*S*2
  float* den   = stats + 131072;                 // B*S
  float* bnst  = den + 8192;                     // 2*E
  float* aout  = bnst + 1024;                    // N*E fp32
  float* x0    = aout;                           // alias (pre-loop only)
  bf16* db_b = (bf16*)(aout + (size_t)Nz * Ez);  // B*S*S
  bf16* Rqk  = db_b + (size_t)Bz * Sz * Sz;      // union region: qk+aw | ff1
  bf16* qk   = Rqk;                              // N*1024
  bf16* aw   = Rqk + (size_t)Nz * 1024;          // B*S*S
  bf16* ff1  = Rqk;                              // N*FF (aliases qk+aw, disjoint lifetime)
  bf16* xb   = Rqk + (size_t)Nz * FFz;           // N*E
  bf16* xT   = xb + (size_t)Nz * Ez;             // B*E*S
  bf16* srcb = xT + (size_t)Bz * Ez * Sz;        // N*IN
  bf16* wpr  = srcb + (size_t)Nz * INz;          // E*IN
  bf16* wqk  = wpr + Ez * INz;                   // 1024*E (q,k rows only)
  bf16* wl1  = wqk + 1024 * Ez;                  // FF*E
  bf16* wl2  = wl1 + FFz * Ez;                   // E*FF

  // weight / input casts
  cast_f2b<<<(Nz * INz) / 256, 256, 0, stream>>>(src, srcb, Nz * INz);
  cast_f2b<<<(Ez * INz + 255) / 256, 256, 0, stream>>>(proj_w, wpr, Ez * INz);
  cast_f2b<<<(1024 * Ez) / 256, 256, 0, stream>>>(in_proj_w, wqk, 1024 * Ez);
  cast_f2b<<<(FFz * Ez) / 256, 256, 0, stream>>>(lin1_w, wl1, FFz * Ez);
  cast_f2b<<<(Ez * FFz) / 256, 256, 0, stream>>>(lin2_w, wl2, Ez * FFz);

  // input projection -> x0 fp32
  gemm_bt<<<dim3(Ez / 128, Nz / 128, 1), 256, 0, stream>>>(
      srcb, wpr, proj_b, x0, nullptr, nullptr, Nz, Ez, INz, 0, 0, 0, 0);
  bn_stats<<<Ez, 256, 0, stream>>>(x0, bnst);
  bn_apply_pe<<<(Nz * Ez) / 256, 256, 0, stream>>>(x0, bnst, bn_g, bn_b, x, xb);
  dist_bias_k<<<Bz * Sz, 256, 0, stream>>>(distances, dist_scale, db_b);

  for (int l = 0; l < Lz; ++l) {
    // transpose layer-entry x (values for PV)
    transpose_xb<<<dim3(Sz / 32, Ez / 32, Bz), 256, 0, stream>>>(xb, xT);
    // q,k projection -> qk bf16 [N,1024]
    gemm_bt<<<dim3(1024 / 128, Nz / 128, 1), 256, 0, stream>>>(
        xb, wqk, in_proj_b, nullptr, qk, nullptr, Nz, 1024, Ez, 0, 0, 0, 0);
    attn_stats2<<<dim3(Sz / 64, Hz, Bz), 256, 0, stream>>>(qk, stats, den);
    scores_bias<<<dim3(Sz / 128, Sz / 128, Bz), 256, 0, stream>>>(qk, db_b, stats, aw, den);
    // PV: batched aw[b] @ x[b]  (values = layer-entry x), renorm by den
    gemm_bt<<<dim3(Ez / 128, Sz / 128, Bz), 256, 0, stream>>>(
        aw, xT, nullptr, aout, nullptr, den,
        Sz, Ez, Sz, (long)Sz * Sz, (long)Ez * Sz, (long)Sz * Ez, 0);
    add_ln<<<Nz, 256, 0, stream>>>(x, aout, n1_g, n1_b, x, xb);
    // FF1 (256^2 8-phase, grid 256 = full GPU)
    gemm256<<<dim3(FFz / 256, Nz / 256), 512, 0, stream>>>(
        xb, wl1, lin1_b, ff1, FFz, Ez, 1);
    gemm_bt<<<dim3(Ez / 128, Nz / 128, 1), 256, 0, stream>>>(
        ff1, wl2, lin2_b, aout, nullptr, nullptr, Nz, Ez, FFz, 0, 0, 0, 0);
    add_ln<<<Nz, 256, 0, stream>>>(x, aout, n2_g, n2_b, x, xb);
  }
}